// Round 1
// 252.077 us; speedup vs baseline: 1.0025x; 1.0025x over previous
//
#include <hip/hip_runtime.h>

typedef __attribute__((ext_vector_type(8))) short bf16x8;
typedef __attribute__((ext_vector_type(4))) float f32x4;

__device__ __forceinline__ float bf2f(unsigned short u) {
    unsigned int x = ((unsigned int)u) << 16;
    float f;
    __builtin_memcpy(&f, &x, 4);
    return f;
}
__device__ __forceinline__ unsigned short f2bf(float f) {
    unsigned int x;
    __builtin_memcpy(&x, &f, 4);
    x += 0x7FFFu + ((x >> 16) & 1u);
    return (unsigned short)(x >> 16);
}

// Async global->LDS: HW writes lds[base + lane*16]; gptr is per-lane.
#define GLOAD_LDS16(gp, lp)                                      \
    __builtin_amdgcn_global_load_lds(                            \
        (const __attribute__((address_space(1))) void*)(gp),     \
        (__attribute__((address_space(3))) void*)(lp), 16, 0, 0)

// -------------------------------------------------------------------------
// float32 -> bf16 cast, 4 elements/thread
__global__ __launch_bounds__(256) void cast_f32_bf16(
    const float* __restrict__ in, unsigned short* __restrict__ out, int n) {
    int i = (blockIdx.x * 256 + threadIdx.x) * 4;
    if (i >= n) return;
    float4 v = *(const float4*)(in + i);
    out[i + 0] = f2bf(v.x);
    out[i + 1] = f2bf(v.y);
    out[i + 2] = f2bf(v.z);
    out[i + 3] = f2bf(v.w);
}

// -------------------------------------------------------------------------
// W_eff[n][k] = bf16( W[n][k] + (1/16) * sum_r BB[n][r] * A[r][k] ), float32 in.
__global__ __launch_bounds__(256) void fold_lora(
    const float* __restrict__ W, const float* __restrict__ Ain,
    const float* __restrict__ Bin, unsigned short* __restrict__ Weff, int NK) {
    int idx = blockIdx.x * 256 + threadIdx.x;
    if (idx >= NK) return;
    int n = idx >> 10;
    int k = idx & 1023;
    float s = 0.f;
#pragma unroll
    for (int r = 0; r < 16; ++r)
        s += Bin[n * 16 + r] * Ain[r * 1024 + k];
    Weff[idx] = f2bf(W[idx] + 0.0625f * s);
}

// -------------------------------------------------------------------------
// C[M][N] = A[M][K] @ B[N][K]^T + bias[N].  A,B bf16; bias float; fp32 acc.
// m97 structure: global_load_lds width=16 staging, 2 barriers per K-step.
template <bool F32OUT>
__global__ __launch_bounds__(256) void gemm_bt_bias(
    const unsigned short* __restrict__ A, const unsigned short* __restrict__ B,
    const float* __restrict__ bias, unsigned short* __restrict__ Cb,
    float* __restrict__ Cf, int M, int N, int K) {
    __shared__ unsigned short sA[128 * 32];
    __shared__ unsigned short sB[128 * 32];
    const int tid = threadIdx.x;
    const int wave = tid >> 6, lane = tid & 63;
    const int quad = lane >> 4, l16 = lane & 15;
    const int m0 = blockIdx.y * 128, n0 = blockIdx.x * 128;
    const int wm = (wave & 1) * 64, wn = (wave >> 1) * 64;

    // Staging map: lane -> row (lane>>2) within the wave's 32-row chunk,
    // col (lane&3)*8.  LDS dest = wave base + lane*16B, which is exactly
    // row*(32 shorts) + col -- the linear layout global_load_lds writes.
    const int srow = wave * 32 + (lane >> 2);
    const int scol = (lane & 3) * 8;
    const unsigned short* Ag = A + (size_t)(m0 + srow) * K + scol;
    const unsigned short* Bg = B + (size_t)(n0 + srow) * K + scol;
    unsigned short* sAw = sA + wave * 1024;
    unsigned short* sBw = sB + wave * 1024;
    const size_t kjump = (size_t)16 * K;

    f32x4 acc[4][4];
#pragma unroll
    for (int i = 0; i < 4; ++i)
#pragma unroll
        for (int j = 0; j < 4; ++j) acc[i][j] = (f32x4){0.f, 0.f, 0.f, 0.f};

    for (int k0 = 0; k0 < K; k0 += 32) {
        __syncthreads();  // previous tile's LDS reads done
        GLOAD_LDS16(Ag + k0, sAw);
        GLOAD_LDS16(Ag + k0 + kjump, sAw + 512);
        GLOAD_LDS16(Bg + k0, sBw);
        GLOAD_LDS16(Bg + k0 + kjump, sBw + 512);
        __syncthreads();  // drains vmcnt(0): tile resident
        bf16x8 af[4], bfr[4];
#pragma unroll
        for (int mi = 0; mi < 4; ++mi)
            af[mi] = *(const bf16x8*)&sA[(wm + mi * 16 + l16) * 32 + quad * 8];
#pragma unroll
        for (int ni = 0; ni < 4; ++ni)
            bfr[ni] = *(const bf16x8*)&sB[(wn + ni * 16 + l16) * 32 + quad * 8];
#pragma unroll
        for (int mi = 0; mi < 4; ++mi)
#pragma unroll
            for (int ni = 0; ni < 4; ++ni)
                acc[mi][ni] = __builtin_amdgcn_mfma_f32_16x16x32_bf16(
                    af[mi], bfr[ni], acc[mi][ni], 0, 0, 0);
    }
    float bv[4];
#pragma unroll
    for (int ni = 0; ni < 4; ++ni) bv[ni] = bias[n0 + wn + ni * 16 + l16];
#pragma unroll
    for (int mi = 0; mi < 4; ++mi)
#pragma unroll
        for (int ni = 0; ni < 4; ++ni)
#pragma unroll
            for (int r = 0; r < 4; ++r) {
                int row = m0 + wm + mi * 16 + quad * 4 + r;
                int col = n0 + wn + ni * 16 + l16;
                float val = acc[mi][ni][r] + bv[ni];
                if (F32OUT)
                    Cf[(size_t)row * N + col] = val;
                else
                    Cb[(size_t)row * N + col] = f2bf(val);
            }
}

// -------------------------------------------------------------------------
// Vt[(b*16+h)][d][t] = qkv[b*2048+t][2048 + h*64 + d]   (bf16, verified r3)
__global__ __launch_bounds__(256) void transpose_v(
    const unsigned short* __restrict__ qkv, unsigned short* __restrict__ Vt) {
    const int b = blockIdx.z, h = blockIdx.y, t0 = blockIdx.x * 64;
    __shared__ unsigned short tile[64][68];
    const int tid = threadIdx.x;
    const int r = tid >> 3, c8 = (tid & 7) * 8;
    const unsigned short* src = qkv + (size_t)(b * 2048) * 3072 + 2048 + h * 64;
#pragma unroll
    for (int p = 0; p < 2; ++p) {
        int t = p * 32 + r;
        const unsigned short* s = src + (size_t)(t0 + t) * 3072 + c8;
#pragma unroll
        for (int j = 0; j < 8; ++j) tile[t][c8 + j] = s[j];
    }
    __syncthreads();
    unsigned short* dst = Vt + (size_t)((b * 16 + h) * 64) * 2048;
#pragma unroll
    for (int p = 0; p < 2; ++p) {
        int d = p * 32 + r;
        unsigned short* o = dst + (size_t)d * 2048 + t0 + c8;
#pragma unroll
        for (int j = 0; j < 8; ++j) o[j] = tile[c8 + j][d];
    }
}

// -------------------------------------------------------------------------
// Flash attention v3: block = 4 waves = 64 q-rows of one (b,h); kv-tiles of 64.
// Single-buffered LDS K/V staging (V pre-transposed in global Vt -> all-b128
// LDS traffic, no scatter). Register prefetch of tile i+1 overlaps compute.
// No online max (|s*csc| < ~3); denom reduced once at the end.
__global__ __launch_bounds__(256) void attn_kernel(
    const unsigned short* __restrict__ qkv,  // [4096][3072] bf16
    const unsigned short* __restrict__ Vt,   // [32][64][2048] bf16
    unsigned short* __restrict__ y) {        // [4096][1024] bf16
    const int b = blockIdx.z, h = blockIdx.y;
    const int qblk = 31 - blockIdx.x;  // long blocks dispatch first
    const int w = threadIdx.x >> 6, lane = threadIdx.x & 63;
    const int quad = lane >> 4, l16 = lane & 15;
    const int q0 = qblk * 64 + w * 16;
    const int ntiles = qblk + 1;

    __shared__ unsigned short sK[64 * 72];     // [kv][d]
    __shared__ unsigned short sV[64 * 72];     // [d][kv]
    __shared__ unsigned short sP[4][16 * 72];  // per-wave P [q][kv]

    const unsigned short* Qb = qkv + (size_t)(b * 2048) * 3072 + h * 64;
    const unsigned short* Kg = Qb + 1024;
    const unsigned short* Vg = Vt + (size_t)((b * 16 + h) * 64) * 2048;

    const int rlo = threadIdx.x >> 3;       // 0..31
    const int c8 = (threadIdx.x & 7) * 8;   // 0..56

    bf16x8 qf0 = *(const bf16x8*)(Qb + (size_t)(q0 + l16) * 3072 + quad * 8);
    bf16x8 qf1 = *(const bf16x8*)(Qb + (size_t)(q0 + l16) * 3072 + 32 + quad * 8);

    f32x4 o[4];
    float lacc[4];
#pragma unroll
    for (int nt = 0; nt < 4; ++nt) o[nt] = (f32x4){0.f, 0.f, 0.f, 0.f};
#pragma unroll
    for (int r = 0; r < 4; ++r) lacc[r] = 0.f;

    const float csc = 0.125f * 1.44269504088896340736f;  // (1/sqrt 64)*log2(e)

    bf16x8 kr0 = *(const bf16x8*)(Kg + (size_t)rlo * 3072 + c8);
    bf16x8 kr1 = *(const bf16x8*)(Kg + (size_t)(rlo + 32) * 3072 + c8);
    bf16x8 vr0 = *(const bf16x8*)(Vg + (size_t)rlo * 2048 + c8);
    bf16x8 vr1 = *(const bf16x8*)(Vg + (size_t)(rlo + 32) * 2048 + c8);

    for (int it = 0; it < ntiles; ++it) {
        const int kv0 = it * 64;
        __syncthreads();  // buffer free
        *(bf16x8*)&sK[rlo * 72 + c8] = kr0;
        *(bf16x8*)&sK[(rlo + 32) * 72 + c8] = kr1;
        *(bf16x8*)&sV[rlo * 72 + c8] = vr0;
        *(bf16x8*)&sV[(rlo + 32) * 72 + c8] = vr1;
        if (it + 1 < ntiles) {  // prefetch next tile; overlaps compute below
            const int nx = kv0 + 64;
            kr0 = *(const bf16x8*)(Kg + (size_t)(nx + rlo) * 3072 + c8);
            kr1 = *(const bf16x8*)(Kg + (size_t)(nx + rlo + 32) * 3072 + c8);
            vr0 = *(const bf16x8*)(Vg + (size_t)rlo * 2048 + nx + c8);
            vr1 = *(const bf16x8*)(Vg + (size_t)(rlo + 32) * 2048 + nx + c8);
        }
        __syncthreads();  // buffer ready

        f32x4 S[4];
#pragma unroll
        for (int f = 0; f < 4; ++f) {
            bf16x8 klo = *(const bf16x8*)&sK[(f * 16 + l16) * 72 + quad * 8];
            bf16x8 khi = *(const bf16x8*)&sK[(f * 16 + l16) * 72 + 32 + quad * 8];
            S[f] = (f32x4){0.f, 0.f, 0.f, 0.f};
            S[f] = __builtin_amdgcn_mfma_f32_16x16x32_bf16(qf0, klo, S[f], 0, 0, 0);
            S[f] = __builtin_amdgcn_mfma_f32_16x16x32_bf16(qf1, khi, S[f], 0, 0, 0);
        }
        if (it == qblk) {  // only the diagonal tile needs the causal mask
#pragma unroll
            for (int f = 0; f < 4; ++f)
#pragma unroll
                for (int r = 0; r < 4; ++r) {
                    int col = kv0 + f * 16 + l16;
                    int qr = q0 + quad * 4 + r;
                    float p = (col <= qr) ? exp2f(S[f][r] * csc) : 0.f;
                    lacc[r] += p;
                    sP[w][(quad * 4 + r) * 72 + f * 16 + l16] = f2bf(p);
                }
        } else {
#pragma unroll
            for (int f = 0; f < 4; ++f)
#pragma unroll
                for (int r = 0; r < 4; ++r) {
                    float p = exp2f(S[f][r] * csc);
                    lacc[r] += p;
                    sP[w][(quad * 4 + r) * 72 + f * 16 + l16] = f2bf(p);
                }
        }
        asm volatile("" ::: "memory");  // order P stores before reload
        bf16x8 pf0 = *(const bf16x8*)&sP[w][l16 * 72 + quad * 8];
        bf16x8 pf1 = *(const bf16x8*)&sP[w][l16 * 72 + 32 + quad * 8];
#pragma unroll
        for (int nt = 0; nt < 4; ++nt) {
            bf16x8 v0 = *(const bf16x8*)&sV[(nt * 16 + l16) * 72 + quad * 8];
            bf16x8 v1 = *(const bf16x8*)&sV[(nt * 16 + l16) * 72 + 32 + quad * 8];
            o[nt] = __builtin_amdgcn_mfma_f32_16x16x32_bf16(pf0, v0, o[nt], 0, 0, 0);
            o[nt] = __builtin_amdgcn_mfma_f32_16x16x32_bf16(pf1, v1, o[nt], 0, 0, 0);
        }
    }

    float lt[4];
#pragma unroll
    for (int r = 0; r < 4; ++r) lt[r] = lacc[r];
#pragma unroll
    for (int d = 1; d < 16; d <<= 1)
#pragma unroll
        for (int r = 0; r < 4; ++r) lt[r] += __shfl_xor(lt[r], d);

    unsigned short* yb = y + (size_t)(b * 2048) * 1024 + h * 64;
#pragma unroll
    for (int nt = 0; nt < 4; ++nt)
#pragma unroll
        for (int r = 0; r < 4; ++r)
            yb[(size_t)(q0 + quad * 4 + r) * 1024 + nt * 16 + l16] =
                f2bf(o[nt][r] / lt[r]);
}

// -------------------------------------------------------------------------
extern "C" void kernel_launch(void* const* d_in, const int* in_sizes, int n_in,
                              void* d_out, int out_size, void* d_ws, size_t ws_size,
                              hipStream_t stream) {
    const float* x       = (const float*)d_in[0];
    const float* w_attn  = (const float*)d_in[1];
    const float* b_attn  = (const float*)d_in[2];
    const float* la_attn = (const float*)d_in[3];
    const float* lb_attn = (const float*)d_in[4];
    const float* w_proj  = (const float*)d_in[5];
    const float* b_proj  = (const float*)d_in[6];
    const float* la_proj = (const float*)d_in[7];
    const float* lb_proj = (const float*)d_in[8];
    float* out = (float*)d_out;

    char* w = (char*)d_ws;
    unsigned short* xb        = (unsigned short*)w; w += (size_t)4096 * 1024 * 2;
    unsigned short* Weff_attn = (unsigned short*)w; w += (size_t)3072 * 1024 * 2;
    unsigned short* Weff_proj = (unsigned short*)w; w += (size_t)1024 * 1024 * 2;
    unsigned short* qkv       = (unsigned short*)w; w += (size_t)4096 * 3072 * 2;
    unsigned short* Vt        = (unsigned short*)w; w += (size_t)32 * 64 * 2048 * 2;
    unsigned short* y         = (unsigned short*)w; w += (size_t)4096 * 1024 * 2;

    cast_f32_bf16<<<4096, 256, 0, stream>>>(x, xb, 4096 * 1024);
    fold_lora<<<(3072 * 1024) / 256, 256, 0, stream>>>(w_attn, la_attn, lb_attn,
                                                       Weff_attn, 3072 * 1024);
    fold_lora<<<(1024 * 1024) / 256, 256, 0, stream>>>(w_proj, la_proj, lb_proj,
                                                       Weff_proj, 1024 * 1024);
    gemm_bt_bias<false><<<dim3(24, 32), 256, 0, stream>>>(
        xb, Weff_attn, b_attn, qkv, (float*)nullptr, 4096, 3072, 1024);
    transpose_v<<<dim3(32, 16, 2), 256, 0, stream>>>(qkv, Vt);
    attn_kernel<<<dim3(32, 16, 2), 256, 0, stream>>>(qkv, Vt, y);
    gemm_bt_bias<true><<<dim3(8, 32), 256, 0, stream>>>(
        y, Weff_proj, b_proj, (unsigned short*)nullptr, out, 4096, 1024, 1024);
}

// Round 2
// 228.344 us; speedup vs baseline: 1.1067x; 1.1039x over previous
//
#include <hip/hip_runtime.h>

typedef __attribute__((ext_vector_type(8))) short bf16x8;
typedef __attribute__((ext_vector_type(4))) float f32x4;

__device__ __forceinline__ float bf2f(unsigned short u) {
    unsigned int x = ((unsigned int)u) << 16;
    float f;
    __builtin_memcpy(&f, &x, 4);
    return f;
}
__device__ __forceinline__ unsigned short f2bf(float f) {
    unsigned int x;
    __builtin_memcpy(&x, &f, 4);
    x += 0x7FFFu + ((x >> 16) & 1u);
    return (unsigned short)(x >> 16);
}

// Async global->LDS: HW writes lds[base + lane*16]; gptr is per-lane.
#define GLOAD_LDS16(gp, lp)                                      \
    __builtin_amdgcn_global_load_lds(                            \
        (const __attribute__((address_space(1))) void*)(gp),     \
        (__attribute__((address_space(3))) void*)(lp), 16, 0, 0)

// -------------------------------------------------------------------------
// float32 -> bf16 cast, 4 elements/thread
__global__ __launch_bounds__(256) void cast_f32_bf16(
    const float* __restrict__ in, unsigned short* __restrict__ out, int n) {
    int i = (blockIdx.x * 256 + threadIdx.x) * 4;
    if (i >= n) return;
    float4 v = *(const float4*)(in + i);
    out[i + 0] = f2bf(v.x);
    out[i + 1] = f2bf(v.y);
    out[i + 2] = f2bf(v.z);
    out[i + 3] = f2bf(v.w);
}

// -------------------------------------------------------------------------
// W_eff[n][k] = bf16( W[n][k] + (1/16) * sum_r BB[n][r] * A[r][k] ), float32 in.
__global__ __launch_bounds__(256) void fold_lora(
    const float* __restrict__ W, const float* __restrict__ Ain,
    const float* __restrict__ Bin, unsigned short* __restrict__ Weff, int NK) {
    int idx = blockIdx.x * 256 + threadIdx.x;
    if (idx >= NK) return;
    int n = idx >> 10;
    int k = idx & 1023;
    float s = 0.f;
#pragma unroll
    for (int r = 0; r < 16; ++r)
        s += Bin[n * 16 + r] * Ain[r * 1024 + k];
    Weff[idx] = f2bf(W[idx] + 0.0625f * s);
}

// -------------------------------------------------------------------------
// C[M][N] = A[M][K] @ B[N][K]^T + bias[N].  A,B bf16; bias float; fp32 acc.
// m97 structure: global_load_lds width=16 staging, 2 barriers per K-step.
template <bool F32OUT>
__global__ __launch_bounds__(256) void gemm_bt_bias(
    const unsigned short* __restrict__ A, const unsigned short* __restrict__ B,
    const float* __restrict__ bias, unsigned short* __restrict__ Cb,
    float* __restrict__ Cf, int M, int N, int K) {
    __shared__ unsigned short sA[128 * 32];
    __shared__ unsigned short sB[128 * 32];
    const int tid = threadIdx.x;
    const int wave = tid >> 6, lane = tid & 63;
    const int quad = lane >> 4, l16 = lane & 15;
    const int m0 = blockIdx.y * 128, n0 = blockIdx.x * 128;
    const int wm = (wave & 1) * 64, wn = (wave >> 1) * 64;

    const int srow = wave * 32 + (lane >> 2);
    const int scol = (lane & 3) * 8;
    const unsigned short* Ag = A + (size_t)(m0 + srow) * K + scol;
    const unsigned short* Bg = B + (size_t)(n0 + srow) * K + scol;
    unsigned short* sAw = sA + wave * 1024;
    unsigned short* sBw = sB + wave * 1024;
    const size_t kjump = (size_t)16 * K;

    f32x4 acc[4][4];
#pragma unroll
    for (int i = 0; i < 4; ++i)
#pragma unroll
        for (int j = 0; j < 4; ++j) acc[i][j] = (f32x4){0.f, 0.f, 0.f, 0.f};

    for (int k0 = 0; k0 < K; k0 += 32) {
        __syncthreads();  // previous tile's LDS reads done
        GLOAD_LDS16(Ag + k0, sAw);
        GLOAD_LDS16(Ag + k0 + kjump, sAw + 512);
        GLOAD_LDS16(Bg + k0, sBw);
        GLOAD_LDS16(Bg + k0 + kjump, sBw + 512);
        __syncthreads();  // drains vmcnt(0): tile resident
        bf16x8 af[4], bfr[4];
#pragma unroll
        for (int mi = 0; mi < 4; ++mi)
            af[mi] = *(const bf16x8*)&sA[(wm + mi * 16 + l16) * 32 + quad * 8];
#pragma unroll
        for (int ni = 0; ni < 4; ++ni)
            bfr[ni] = *(const bf16x8*)&sB[(wn + ni * 16 + l16) * 32 + quad * 8];
#pragma unroll
        for (int mi = 0; mi < 4; ++mi)
#pragma unroll
            for (int ni = 0; ni < 4; ++ni)
                acc[mi][ni] = __builtin_amdgcn_mfma_f32_16x16x32_bf16(
                    af[mi], bfr[ni], acc[mi][ni], 0, 0, 0);
    }
    float bv[4];
#pragma unroll
    for (int ni = 0; ni < 4; ++ni) bv[ni] = bias[n0 + wn + ni * 16 + l16];
#pragma unroll
    for (int mi = 0; mi < 4; ++mi)
#pragma unroll
        for (int ni = 0; ni < 4; ++ni)
#pragma unroll
            for (int r = 0; r < 4; ++r) {
                int row = m0 + wm + mi * 16 + quad * 4 + r;
                int col = n0 + wn + ni * 16 + l16;
                float val = acc[mi][ni][r] + bv[ni];
                if (F32OUT)
                    Cf[(size_t)row * N + col] = val;
                else
                    Cb[(size_t)row * N + col] = f2bf(val);
            }
}

// -------------------------------------------------------------------------
// Vt[(b*16+h)][d][t] = qkv[b*2048+t][2048 + h*64 + d]   (bf16, verified r3)
__global__ __launch_bounds__(256) void transpose_v(
    const unsigned short* __restrict__ qkv, unsigned short* __restrict__ Vt) {
    const int b = blockIdx.z, h = blockIdx.y, t0 = blockIdx.x * 64;
    __shared__ unsigned short tile[64][68];
    const int tid = threadIdx.x;
    const int r = tid >> 3, c8 = (tid & 7) * 8;
    const unsigned short* src = qkv + (size_t)(b * 2048) * 3072 + 2048 + h * 64;
#pragma unroll
    for (int p = 0; p < 2; ++p) {
        int t = p * 32 + r;
        const unsigned short* s = src + (size_t)(t0 + t) * 3072 + c8;
#pragma unroll
        for (int j = 0; j < 8; ++j) tile[t][c8 + j] = s[j];
    }
    __syncthreads();
    unsigned short* dst = Vt + (size_t)((b * 16 + h) * 64) * 2048;
#pragma unroll
    for (int p = 0; p < 2; ++p) {
        int d = p * 32 + r;
        unsigned short* o = dst + (size_t)d * 2048 + t0 + c8;
#pragma unroll
        for (int j = 0; j < 8; ++j) o[j] = tile[c8 + j][d];
    }
}

// -------------------------------------------------------------------------
// Flash attention v4: complementary-pair scheduling.
// Grid x = 16; each block runs TWO q-blocks: qblk = 31-x (long) then x
// (short), so every block does exactly 33 kv-tile units regardless of x.
// This removes the CU-level work imbalance that capped v3 at ~18% occupancy
// (blocks congruent mod 32 shared one qblk, so some CUs got 4x32 tiles and
// others 4x1). Tile body unchanged from v3: single-buffered LDS K/V with
// register prefetch, no online max, denom reduced once at the end.
__global__ __launch_bounds__(256) void attn_kernel(
    const unsigned short* __restrict__ qkv,  // [4096][3072] bf16
    const unsigned short* __restrict__ Vt,   // [32][64][2048] bf16
    unsigned short* __restrict__ y) {        // [4096][1024] bf16
    const int b = blockIdx.z, h = blockIdx.y;
    const int w = threadIdx.x >> 6, lane = threadIdx.x & 63;
    const int quad = lane >> 4, l16 = lane & 15;

    __shared__ unsigned short sK[64 * 72];     // [kv][d]
    __shared__ unsigned short sV[64 * 72];     // [d][kv]
    __shared__ unsigned short sP[4][16 * 72];  // per-wave P [q][kv]

    const unsigned short* Qb = qkv + (size_t)(b * 2048) * 3072 + h * 64;
    const unsigned short* Kg = Qb + 1024;
    const unsigned short* Vg = Vt + (size_t)((b * 16 + h) * 64) * 2048;

    const int rlo = threadIdx.x >> 3;       // 0..31
    const int c8 = (threadIdx.x & 7) * 8;   // 0..56

    const float csc = 0.125f * 1.44269504088896340736f;  // (1/sqrt 64)*log2(e)

#pragma unroll 1
    for (int pass = 0; pass < 2; ++pass) {
        const int qblk = pass == 0 ? (31 - (int)blockIdx.x) : (int)blockIdx.x;
        const int q0 = qblk * 64 + w * 16;
        const int ntiles = qblk + 1;

        bf16x8 qf0 = *(const bf16x8*)(Qb + (size_t)(q0 + l16) * 3072 + quad * 8);
        bf16x8 qf1 = *(const bf16x8*)(Qb + (size_t)(q0 + l16) * 3072 + 32 + quad * 8);

        f32x4 o[4];
        float lacc[4];
#pragma unroll
        for (int nt = 0; nt < 4; ++nt) o[nt] = (f32x4){0.f, 0.f, 0.f, 0.f};
#pragma unroll
        for (int r = 0; r < 4; ++r) lacc[r] = 0.f;

        bf16x8 kr0 = *(const bf16x8*)(Kg + (size_t)rlo * 3072 + c8);
        bf16x8 kr1 = *(const bf16x8*)(Kg + (size_t)(rlo + 32) * 3072 + c8);
        bf16x8 vr0 = *(const bf16x8*)(Vg + (size_t)rlo * 2048 + c8);
        bf16x8 vr1 = *(const bf16x8*)(Vg + (size_t)(rlo + 32) * 2048 + c8);

        for (int it = 0; it < ntiles; ++it) {
            const int kv0 = it * 64;
            __syncthreads();  // buffer free (also guards cross-pass reuse)
            *(bf16x8*)&sK[rlo * 72 + c8] = kr0;
            *(bf16x8*)&sK[(rlo + 32) * 72 + c8] = kr1;
            *(bf16x8*)&sV[rlo * 72 + c8] = vr0;
            *(bf16x8*)&sV[(rlo + 32) * 72 + c8] = vr1;
            if (it + 1 < ntiles) {  // prefetch next tile; overlaps compute below
                const int nx = kv0 + 64;
                kr0 = *(const bf16x8*)(Kg + (size_t)(nx + rlo) * 3072 + c8);
                kr1 = *(const bf16x8*)(Kg + (size_t)(nx + rlo + 32) * 3072 + c8);
                vr0 = *(const bf16x8*)(Vg + (size_t)rlo * 2048 + nx + c8);
                vr1 = *(const bf16x8*)(Vg + (size_t)(rlo + 32) * 2048 + nx + c8);
            }
            __syncthreads();  // buffer ready

            f32x4 S[4];
#pragma unroll
            for (int f = 0; f < 4; ++f) {
                bf16x8 klo = *(const bf16x8*)&sK[(f * 16 + l16) * 72 + quad * 8];
                bf16x8 khi = *(const bf16x8*)&sK[(f * 16 + l16) * 72 + 32 + quad * 8];
                S[f] = (f32x4){0.f, 0.f, 0.f, 0.f};
                S[f] = __builtin_amdgcn_mfma_f32_16x16x32_bf16(qf0, klo, S[f], 0, 0, 0);
                S[f] = __builtin_amdgcn_mfma_f32_16x16x32_bf16(qf1, khi, S[f], 0, 0, 0);
            }
            if (it == qblk) {  // only the diagonal tile needs the causal mask
#pragma unroll
                for (int f = 0; f < 4; ++f)
#pragma unroll
                    for (int r = 0; r < 4; ++r) {
                        int col = kv0 + f * 16 + l16;
                        int qr = q0 + quad * 4 + r;
                        float p = (col <= qr) ? exp2f(S[f][r] * csc) : 0.f;
                        lacc[r] += p;
                        sP[w][(quad * 4 + r) * 72 + f * 16 + l16] = f2bf(p);
                    }
            } else {
#pragma unroll
                for (int f = 0; f < 4; ++f)
#pragma unroll
                    for (int r = 0; r < 4; ++r) {
                        float p = exp2f(S[f][r] * csc);
                        lacc[r] += p;
                        sP[w][(quad * 4 + r) * 72 + f * 16 + l16] = f2bf(p);
                    }
            }
            asm volatile("" ::: "memory");  // order P stores before reload
            bf16x8 pf0 = *(const bf16x8*)&sP[w][l16 * 72 + quad * 8];
            bf16x8 pf1 = *(const bf16x8*)&sP[w][l16 * 72 + 32 + quad * 8];
#pragma unroll
            for (int nt = 0; nt < 4; ++nt) {
                bf16x8 v0 = *(const bf16x8*)&sV[(nt * 16 + l16) * 72 + quad * 8];
                bf16x8 v1 = *(const bf16x8*)&sV[(nt * 16 + l16) * 72 + 32 + quad * 8];
                o[nt] = __builtin_amdgcn_mfma_f32_16x16x32_bf16(pf0, v0, o[nt], 0, 0, 0);
                o[nt] = __builtin_amdgcn_mfma_f32_16x16x32_bf16(pf1, v1, o[nt], 0, 0, 0);
            }
        }

        float lt[4];
#pragma unroll
        for (int r = 0; r < 4; ++r) lt[r] = lacc[r];
#pragma unroll
        for (int d = 1; d < 16; d <<= 1)
#pragma unroll
            for (int r = 0; r < 4; ++r) lt[r] += __shfl_xor(lt[r], d);

        unsigned short* yb = y + (size_t)(b * 2048) * 1024 + h * 64;
#pragma unroll
        for (int nt = 0; nt < 4; ++nt)
#pragma unroll
            for (int r = 0; r < 4; ++r)
                yb[(size_t)(q0 + quad * 4 + r) * 1024 + nt * 16 + l16] =
                    f2bf(o[nt][r] / lt[r]);
    }
}

// -------------------------------------------------------------------------
extern "C" void kernel_launch(void* const* d_in, const int* in_sizes, int n_in,
                              void* d_out, int out_size, void* d_ws, size_t ws_size,
                              hipStream_t stream) {
    const float* x       = (const float*)d_in[0];
    const float* w_attn  = (const float*)d_in[1];
    const float* b_attn  = (const float*)d_in[2];
    const float* la_attn = (const float*)d_in[3];
    const float* lb_attn = (const float*)d_in[4];
    const float* w_proj  = (const float*)d_in[5];
    const float* b_proj  = (const float*)d_in[6];
    const float* la_proj = (const float*)d_in[7];
    const float* lb_proj = (const float*)d_in[8];
    float* out = (float*)d_out;

    char* w = (char*)d_ws;
    unsigned short* xb        = (unsigned short*)w; w += (size_t)4096 * 1024 * 2;
    unsigned short* Weff_attn = (unsigned short*)w; w += (size_t)3072 * 1024 * 2;
    unsigned short* Weff_proj = (unsigned short*)w; w += (size_t)1024 * 1024 * 2;
    unsigned short* qkv       = (unsigned short*)w; w += (size_t)4096 * 3072 * 2;
    unsigned short* Vt        = (unsigned short*)w; w += (size_t)32 * 64 * 2048 * 2;
    unsigned short* y         = (unsigned short*)w; w += (size_t)4096 * 1024 * 2;

    cast_f32_bf16<<<4096, 256, 0, stream>>>(x, xb, 4096 * 1024);
    fold_lora<<<(3072 * 1024) / 256, 256, 0, stream>>>(w_attn, la_attn, lb_attn,
                                                       Weff_attn, 3072 * 1024);
    fold_lora<<<(1024 * 1024) / 256, 256, 0, stream>>>(w_proj, la_proj, lb_proj,
                                                       Weff_proj, 1024 * 1024);
    gemm_bt_bias<false><<<dim3(24, 32), 256, 0, stream>>>(
        xb, Weff_attn, b_attn, qkv, (float*)nullptr, 4096, 3072, 1024);
    transpose_v<<<dim3(32, 16, 2), 256, 0, stream>>>(qkv, Vt);
    attn_kernel<<<dim3(16, 16, 2), 256, 0, stream>>>(qkv, Vt, y);
    gemm_bt_bias<true><<<dim3(8, 32), 256, 0, stream>>>(
        y, Weff_proj, b_proj, (unsigned short*)nullptr, out, 4096, 1024, 1024);
}

// Round 3
// 222.661 us; speedup vs baseline: 1.1350x; 1.0255x over previous
//
#include <hip/hip_runtime.h>

typedef __attribute__((ext_vector_type(8))) short bf16x8;
typedef __attribute__((ext_vector_type(4))) float f32x4;

__device__ __forceinline__ float bf2f(unsigned short u) {
    unsigned int x = ((unsigned int)u) << 16;
    float f;
    __builtin_memcpy(&f, &x, 4);
    return f;
}
__device__ __forceinline__ unsigned short f2bf(float f) {
    unsigned int x;
    __builtin_memcpy(&x, &f, 4);
    x += 0x7FFFu + ((x >> 16) & 1u);
    return (unsigned short)(x >> 16);
}

// Async global->LDS: HW writes lds[base + lane*16]; gptr is per-lane.
#define GLOAD_LDS16(gp, lp)                                      \
    __builtin_amdgcn_global_load_lds(                            \
        (const __attribute__((address_space(1))) void*)(gp),     \
        (__attribute__((address_space(3))) void*)(lp), 16, 0, 0)

// -------------------------------------------------------------------------
// float32 -> bf16 cast, 4 elements/thread
__global__ __launch_bounds__(256) void cast_f32_bf16(
    const float* __restrict__ in, unsigned short* __restrict__ out, int n) {
    int i = (blockIdx.x * 256 + threadIdx.x) * 4;
    if (i >= n) return;
    float4 v = *(const float4*)(in + i);
    out[i + 0] = f2bf(v.x);
    out[i + 1] = f2bf(v.y);
    out[i + 2] = f2bf(v.z);
    out[i + 3] = f2bf(v.w);
}

// -------------------------------------------------------------------------
// W_eff[n][k] = bf16( W[n][k] + (1/16) * sum_r BB[n][r] * A[r][k] ), float32 in.
__global__ __launch_bounds__(256) void fold_lora(
    const float* __restrict__ W, const float* __restrict__ Ain,
    const float* __restrict__ Bin, unsigned short* __restrict__ Weff, int NK) {
    int idx = blockIdx.x * 256 + threadIdx.x;
    if (idx >= NK) return;
    int n = idx >> 10;
    int k = idx & 1023;
    float s = 0.f;
#pragma unroll
    for (int r = 0; r < 16; ++r)
        s += Bin[n * 16 + r] * Ain[r * 1024 + k];
    Weff[idx] = f2bf(W[idx] + 0.0625f * s);
}

// -------------------------------------------------------------------------
// C[M][N] = A[M][K] @ B[N][K]^T + bias[N].  A,B bf16; bias float; fp32 acc.
// m97 structure: global_load_lds width=16 staging, 2 barriers per K-step.
template <bool F32OUT>
__global__ __launch_bounds__(256) void gemm_bt_bias(
    const unsigned short* __restrict__ A, const unsigned short* __restrict__ B,
    const float* __restrict__ bias, unsigned short* __restrict__ Cb,
    float* __restrict__ Cf, int M, int N, int K) {
    __shared__ unsigned short sA[128 * 32];
    __shared__ unsigned short sB[128 * 32];
    const int tid = threadIdx.x;
    const int wave = tid >> 6, lane = tid & 63;
    const int quad = lane >> 4, l16 = lane & 15;
    const int m0 = blockIdx.y * 128, n0 = blockIdx.x * 128;
    const int wm = (wave & 1) * 64, wn = (wave >> 1) * 64;

    const int srow = wave * 32 + (lane >> 2);
    const int scol = (lane & 3) * 8;
    const unsigned short* Ag = A + (size_t)(m0 + srow) * K + scol;
    const unsigned short* Bg = B + (size_t)(n0 + srow) * K + scol;
    unsigned short* sAw = sA + wave * 1024;
    unsigned short* sBw = sB + wave * 1024;
    const size_t kjump = (size_t)16 * K;

    f32x4 acc[4][4];
#pragma unroll
    for (int i = 0; i < 4; ++i)
#pragma unroll
        for (int j = 0; j < 4; ++j) acc[i][j] = (f32x4){0.f, 0.f, 0.f, 0.f};

    for (int k0 = 0; k0 < K; k0 += 32) {
        __syncthreads();  // previous tile's LDS reads done
        GLOAD_LDS16(Ag + k0, sAw);
        GLOAD_LDS16(Ag + k0 + kjump, sAw + 512);
        GLOAD_LDS16(Bg + k0, sBw);
        GLOAD_LDS16(Bg + k0 + kjump, sBw + 512);
        __syncthreads();  // drains vmcnt(0): tile resident
        bf16x8 af[4], bfr[4];
#pragma unroll
        for (int mi = 0; mi < 4; ++mi)
            af[mi] = *(const bf16x8*)&sA[(wm + mi * 16 + l16) * 32 + quad * 8];
#pragma unroll
        for (int ni = 0; ni < 4; ++ni)
            bfr[ni] = *(const bf16x8*)&sB[(wn + ni * 16 + l16) * 32 + quad * 8];
#pragma unroll
        for (int mi = 0; mi < 4; ++mi)
#pragma unroll
            for (int ni = 0; ni < 4; ++ni)
                acc[mi][ni] = __builtin_amdgcn_mfma_f32_16x16x32_bf16(
                    af[mi], bfr[ni], acc[mi][ni], 0, 0, 0);
    }
    float bv[4];
#pragma unroll
    for (int ni = 0; ni < 4; ++ni) bv[ni] = bias[n0 + wn + ni * 16 + l16];
#pragma unroll
    for (int mi = 0; mi < 4; ++mi)
#pragma unroll
        for (int ni = 0; ni < 4; ++ni)
#pragma unroll
            for (int r = 0; r < 4; ++r) {
                int row = m0 + wm + mi * 16 + quad * 4 + r;
                int col = n0 + wn + ni * 16 + l16;
                float val = acc[mi][ni][r] + bv[ni];
                if (F32OUT)
                    Cf[(size_t)row * N + col] = val;
                else
                    Cb[(size_t)row * N + col] = f2bf(val);
            }
}

// -------------------------------------------------------------------------
// Vt[(b*16+h)][d][t] = qkv[b*2048+t][2048 + h*64 + d]   (bf16, verified r3)
__global__ __launch_bounds__(256) void transpose_v(
    const unsigned short* __restrict__ qkv, unsigned short* __restrict__ Vt) {
    const int b = blockIdx.z, h = blockIdx.y, t0 = blockIdx.x * 64;
    __shared__ unsigned short tile[64][68];
    const int tid = threadIdx.x;
    const int r = tid >> 3, c8 = (tid & 7) * 8;
    const unsigned short* src = qkv + (size_t)(b * 2048) * 3072 + 2048 + h * 64;
#pragma unroll
    for (int p = 0; p < 2; ++p) {
        int t = p * 32 + r;
        const unsigned short* s = src + (size_t)(t0 + t) * 3072 + c8;
#pragma unroll
        for (int j = 0; j < 8; ++j) tile[t][c8 + j] = s[j];
    }
    __syncthreads();
    unsigned short* dst = Vt + (size_t)((b * 16 + h) * 64) * 2048;
#pragma unroll
    for (int p = 0; p < 2; ++p) {
        int d = p * 32 + r;
        unsigned short* o = dst + (size_t)d * 2048 + t0 + c8;
#pragma unroll
        for (int j = 0; j < 8; ++j) o[j] = tile[c8 + j][d];
    }
}

// -------------------------------------------------------------------------
// Flash attention v5: single-pass blocks + balanced qblk permutation.
// Grid = (32,16,2) = 1024 blocks, all resident (4 blocks/CU, 16 waves/CU =
// 4 waves/SIMD -- double v4's concurrency, the latency-hiding this kernel
// lacked). Balance: co-resident blocks are {c, c+256, c+512, c+768} (holds
// for linear AND XCD-round-robin dispatch; established empirically r1->r2).
// These share blockIdx.x and differ in bit3 of bh, so
//   qblk = x ^ (((bh>>3)&1) ? 31 : 0)
// gives each CU qblks {x, 31-x, x, 31-x} = 66 tile-units, uniform across
// CUs, while remaining a permutation of 0..31 within each (b,h).
// Tile body unchanged: single-buffered LDS K/V, register prefetch,
// no online max, denom reduced once at the end.
__global__ __launch_bounds__(256) void attn_kernel(
    const unsigned short* __restrict__ qkv,  // [4096][3072] bf16
    const unsigned short* __restrict__ Vt,   // [32][64][2048] bf16
    unsigned short* __restrict__ y) {        // [4096][1024] bf16
    const int b = blockIdx.z, h = blockIdx.y;
    const int bh = b * 16 + h;
    const int qblk = (int)blockIdx.x ^ (((bh >> 3) & 1) ? 31 : 0);
    const int w = threadIdx.x >> 6, lane = threadIdx.x & 63;
    const int quad = lane >> 4, l16 = lane & 15;
    const int q0 = qblk * 64 + w * 16;
    const int ntiles = qblk + 1;

    __shared__ unsigned short sK[64 * 72];     // [kv][d]
    __shared__ unsigned short sV[64 * 72];     // [d][kv]
    __shared__ unsigned short sP[4][16 * 72];  // per-wave P [q][kv]

    const unsigned short* Qb = qkv + (size_t)(b * 2048) * 3072 + h * 64;
    const unsigned short* Kg = Qb + 1024;
    const unsigned short* Vg = Vt + (size_t)(bh * 64) * 2048;

    const int rlo = threadIdx.x >> 3;       // 0..31
    const int c8 = (threadIdx.x & 7) * 8;   // 0..56

    bf16x8 qf0 = *(const bf16x8*)(Qb + (size_t)(q0 + l16) * 3072 + quad * 8);
    bf16x8 qf1 = *(const bf16x8*)(Qb + (size_t)(q0 + l16) * 3072 + 32 + quad * 8);

    f32x4 o[4];
    float lacc[4];
#pragma unroll
    for (int nt = 0; nt < 4; ++nt) o[nt] = (f32x4){0.f, 0.f, 0.f, 0.f};
#pragma unroll
    for (int r = 0; r < 4; ++r) lacc[r] = 0.f;

    const float csc = 0.125f * 1.44269504088896340736f;  // (1/sqrt 64)*log2(e)

    bf16x8 kr0 = *(const bf16x8*)(Kg + (size_t)rlo * 3072 + c8);
    bf16x8 kr1 = *(const bf16x8*)(Kg + (size_t)(rlo + 32) * 3072 + c8);
    bf16x8 vr0 = *(const bf16x8*)(Vg + (size_t)rlo * 2048 + c8);
    bf16x8 vr1 = *(const bf16x8*)(Vg + (size_t)(rlo + 32) * 2048 + c8);

    for (int it = 0; it < ntiles; ++it) {
        const int kv0 = it * 64;
        __syncthreads();  // buffer free
        *(bf16x8*)&sK[rlo * 72 + c8] = kr0;
        *(bf16x8*)&sK[(rlo + 32) * 72 + c8] = kr1;
        *(bf16x8*)&sV[rlo * 72 + c8] = vr0;
        *(bf16x8*)&sV[(rlo + 32) * 72 + c8] = vr1;
        if (it + 1 < ntiles) {  // prefetch next tile; overlaps compute below
            const int nx = kv0 + 64;
            kr0 = *(const bf16x8*)(Kg + (size_t)(nx + rlo) * 3072 + c8);
            kr1 = *(const bf16x8*)(Kg + (size_t)(nx + rlo + 32) * 3072 + c8);
            vr0 = *(const bf16x8*)(Vg + (size_t)rlo * 2048 + nx + c8);
            vr1 = *(const bf16x8*)(Vg + (size_t)(rlo + 32) * 2048 + nx + c8);
        }
        __syncthreads();  // buffer ready

        f32x4 S[4];
#pragma unroll
        for (int f = 0; f < 4; ++f) {
            bf16x8 klo = *(const bf16x8*)&sK[(f * 16 + l16) * 72 + quad * 8];
            bf16x8 khi = *(const bf16x8*)&sK[(f * 16 + l16) * 72 + 32 + quad * 8];
            S[f] = (f32x4){0.f, 0.f, 0.f, 0.f};
            S[f] = __builtin_amdgcn_mfma_f32_16x16x32_bf16(qf0, klo, S[f], 0, 0, 0);
            S[f] = __builtin_amdgcn_mfma_f32_16x16x32_bf16(qf1, khi, S[f], 0, 0, 0);
        }
        if (it == qblk) {  // only the diagonal tile needs the causal mask
#pragma unroll
            for (int f = 0; f < 4; ++f)
#pragma unroll
                for (int r = 0; r < 4; ++r) {
                    int col = kv0 + f * 16 + l16;
                    int qr = q0 + quad * 4 + r;
                    float p = (col <= qr) ? exp2f(S[f][r] * csc) : 0.f;
                    lacc[r] += p;
                    sP[w][(quad * 4 + r) * 72 + f * 16 + l16] = f2bf(p);
                }
        } else {
#pragma unroll
            for (int f = 0; f < 4; ++f)
#pragma unroll
                for (int r = 0; r < 4; ++r) {
                    float p = exp2f(S[f][r] * csc);
                    lacc[r] += p;
                    sP[w][(quad * 4 + r) * 72 + f * 16 + l16] = f2bf(p);
                }
        }
        asm volatile("" ::: "memory");  // order P stores before reload
        bf16x8 pf0 = *(const bf16x8*)&sP[w][l16 * 72 + quad * 8];
        bf16x8 pf1 = *(const bf16x8*)&sP[w][l16 * 72 + 32 + quad * 8];
#pragma unroll
        for (int nt = 0; nt < 4; ++nt) {
            bf16x8 v0 = *(const bf16x8*)&sV[(nt * 16 + l16) * 72 + quad * 8];
            bf16x8 v1 = *(const bf16x8*)&sV[(nt * 16 + l16) * 72 + 32 + quad * 8];
            o[nt] = __builtin_amdgcn_mfma_f32_16x16x32_bf16(pf0, v0, o[nt], 0, 0, 0);
            o[nt] = __builtin_amdgcn_mfma_f32_16x16x32_bf16(pf1, v1, o[nt], 0, 0, 0);
        }
    }

    float lt[4];
#pragma unroll
    for (int r = 0; r < 4; ++r) lt[r] = lacc[r];
#pragma unroll
    for (int d = 1; d < 16; d <<= 1)
#pragma unroll
        for (int r = 0; r < 4; ++r) lt[r] += __shfl_xor(lt[r], d);

    unsigned short* yb = y + (size_t)(b * 2048) * 1024 + h * 64;
#pragma unroll
    for (int nt = 0; nt < 4; ++nt)
#pragma unroll
        for (int r = 0; r < 4; ++r)
            yb[(size_t)(q0 + quad * 4 + r) * 1024 + nt * 16 + l16] =
                f2bf(o[nt][r] / lt[r]);
}

// -------------------------------------------------------------------------
extern "C" void kernel_launch(void* const* d_in, const int* in_sizes, int n_in,
                              void* d_out, int out_size, void* d_ws, size_t ws_size,
                              hipStream_t stream) {
    const float* x       = (const float*)d_in[0];
    const float* w_attn  = (const float*)d_in[1];
    const float* b_attn  = (const float*)d_in[2];
    const float* la_attn = (const float*)d_in[3];
    const float* lb_attn = (const float*)d_in[4];
    const float* w_proj  = (const float*)d_in[5];
    const float* b_proj  = (const float*)d_in[6];
    const float* la_proj = (const float*)d_in[7];
    const float* lb_proj = (const float*)d_in[8];
    float* out = (float*)d_out;

    char* w = (char*)d_ws;
    unsigned short* xb        = (unsigned short*)w; w += (size_t)4096 * 1024 * 2;
    unsigned short* Weff_attn = (unsigned short*)w; w += (size_t)3072 * 1024 * 2;
    unsigned short* Weff_proj = (unsigned short*)w; w += (size_t)1024 * 1024 * 2;
    unsigned short* qkv       = (unsigned short*)w; w += (size_t)4096 * 3072 * 2;
    unsigned short* Vt        = (unsigned short*)w; w += (size_t)32 * 64 * 2048 * 2;
    unsigned short* y         = (unsigned short*)w; w += (size_t)4096 * 1024 * 2;

    cast_f32_bf16<<<4096, 256, 0, stream>>>(x, xb, 4096 * 1024);
    fold_lora<<<(3072 * 1024) / 256, 256, 0, stream>>>(w_attn, la_attn, lb_attn,
                                                       Weff_attn, 3072 * 1024);
    fold_lora<<<(1024 * 1024) / 256, 256, 0, stream>>>(w_proj, la_proj, lb_proj,
                                                       Weff_proj, 1024 * 1024);
    gemm_bt_bias<false><<<dim3(24, 32), 256, 0, stream>>>(
        xb, Weff_attn, b_attn, qkv, (float*)nullptr, 4096, 3072, 1024);
    transpose_v<<<dim3(32, 16, 2), 256, 0, stream>>>(qkv, Vt);
    attn_kernel<<<dim3(32, 16, 2), 256, 0, stream>>>(qkv, Vt, y);
    gemm_bt_bias<true><<<dim3(8, 32), 256, 0, stream>>>(
        y, Weff_proj, b_proj, (unsigned short*)nullptr, out, 4096, 1024, 1024);
}